// Round 14
// baseline (117.080 us; speedup 1.0000x reference)
//
#include <hip/hip_runtime.h>
#include <hip/hip_bf16.h>

#define D 64
#define LOGB 7            // 128 nodes per bin-bucket
#define BNODES 128
#define GRP6 32           // nodes per k_bucket6 block
#define CH6 1024          // record chunk in k_bucket6
#define TN 64             // nodes per transform block

__device__ __forceinline__ float blo(unsigned u) { return __uint_as_float(u << 16); }
__device__ __forceinline__ float bhi(unsigned u) { return __uint_as_float(u & 0xffff0000u); }
__device__ __forceinline__ ushort f2bfr(float x) {
    __hip_bfloat16 hb = __float2bfloat16(x);     // RNE
    return *reinterpret_cast<ushort*>(&hb);
}

// ---------------- k_zero: replaces hipMemsetAsync (42us anomaly in-graph) ----------------

__global__ __launch_bounds__(256) void k_zero(int* __restrict__ p, int n)
{
    int i = blockIdx.x * 256 + threadIdx.x;
    if (i < n) p[i] = 0;
}

// ---------------- k_hist: standalone dst-bucket histogram ----------------

__global__ __launch_bounds__(256) void k_hist(
    const int* __restrict__ dst, int* __restrict__ cnt, int n_edges, int nbkt)
{
    __shared__ int sc[1024];
    int t = threadIdx.x;
    for (int i = t; i < 1024; i += 256) sc[i] = 0;
    __syncthreads();
    int n4 = n_edges >> 2;
    const int4* d4 = (const int4*)dst;
    int stride = gridDim.x * 256;
    for (int i = blockIdx.x * 256 + t; i < n4; i += stride) {
        int4 d = d4[i];
        atomicAdd(&sc[d.x >> LOGB], 1);
        atomicAdd(&sc[d.y >> LOGB], 1);
        atomicAdd(&sc[d.z >> LOGB], 1);
        atomicAdd(&sc[d.w >> LOGB], 1);
    }
    if (blockIdx.x == 0 && t == 0)
        for (int e = n4 << 2; e < n_edges; ++e) atomicAdd(&cnt[dst[e] >> LOGB], 1);
    __syncthreads();
    for (int i = t; i < nbkt; i += 256) {
        int c = sc[i];
        if (c) atomicAdd(&cnt[i], c);
    }
}

// ---------------- k_bin_scan ----------------

__global__ __launch_bounds__(1024) void k_bin_scan(
    const int* __restrict__ cnt, int* __restrict__ base,
    int* __restrict__ cursor, int nbkt)
{
    int t = threadIdx.x;
    int v = (t < nbkt) ? cnt[t] : 0;
    int lane = t & 63;
    int incl = v;
    #pragma unroll
    for (int o = 1; o < 64; o <<= 1) {
        int u = __shfl_up(incl, o, 64);
        if (lane >= o) incl += u;
    }
    __shared__ int wtot[16];
    if (lane == 63) wtot[t >> 6] = incl;
    __syncthreads();
    int wpre = 0;
    int w = t >> 6;
    for (int i = 0; i < w; ++i) wpre += wtot[i];
    int excl = wpre + incl - v;
    if (t < nbkt) { base[t] = excl; cursor[t] = excl; }
    if (t == nbkt - 1) base[nbkt] = excl + v;
}

// ---------------- k_fused: interleaved scatter/transform blocks ----------------
// Block bid is a scatter block iff (bid % R == 0 && bid/R < nblk); else transform.
// Interleave keeps both resource profiles (LDS-atomics vs VALU) co-resident.

__global__ __launch_bounds__(256) void k_fused(
    // scatter args
    const int* __restrict__ src, const int* __restrict__ dst,
    int* __restrict__ cursor, unsigned* __restrict__ packed,
    int n_edges, int sbits, int nblk, int R,
    // transform args
    const float* __restrict__ feat, const float* __restrict__ W,
    ushort* __restrict__ g, int n_nodes)
{
    __shared__ __align__(16) char smem[45072];
    int t = threadIdx.x;
    int bid = (int)blockIdx.x;
    int sidx = bid / R;
    bool is_scatter = ((bid % R) == 0) && (sidx < nblk);

    if (is_scatter) {
        // ---------------- bin_scatter body (4096-edge chunk) ----------------
        int* s_cnt  = (int*)smem;                       // 1024 ints
        int* s_base = (int*)(smem + 4096);              // 1024 ints
        int* s_gb   = (int*)(smem + 8192);              // 1024 ints
        int* wtot   = (int*)(smem + 12288);             // 4 ints
        unsigned* s_stage = (unsigned*)(smem + 12304);  // 4096 u32
        int* s_addr = (int*)(smem + 28688);             // 4096 ints

        int chbase = sidx * 4096;
        int count = n_edges - chbase;
        if (count > 4096) count = 4096;

        for (int i = t; i < 1024; i += 256) s_cnt[i] = 0;
        __syncthreads();

        #pragma unroll
        for (int k = 0; k < 16; ++k) {
            int i = t + k * 256;
            if (i < count) atomicAdd(&s_cnt[dst[chbase + i] >> LOGB], 1);
        }
        __syncthreads();

        int b4 = t * 4;
        int v0 = s_cnt[b4], v1 = s_cnt[b4 + 1], v2 = s_cnt[b4 + 2], v3 = s_cnt[b4 + 3];
        int ssum = v0 + v1 + v2 + v3;
        int lane = t & 63;
        int incl = ssum;
        #pragma unroll
        for (int o = 1; o < 64; o <<= 1) {
            int u = __shfl_up(incl, o, 64);
            if (lane >= o) incl += u;
        }
        if (lane == 63) wtot[t >> 6] = incl;
        __syncthreads();
        int wpre = 0;
        int w = t >> 6;
        for (int i = 0; i < w; ++i) wpre += wtot[i];
        int excl = wpre + incl - ssum;
        s_base[b4]     = excl;
        s_base[b4 + 1] = excl + v0;
        s_base[b4 + 2] = excl + v0 + v1;
        s_base[b4 + 3] = excl + v0 + v1 + v2;
        __syncthreads();

        for (int i = t; i < 1024; i += 256) {
            int c = s_cnt[i];
            s_gb[i] = c ? atomicAdd(&cursor[i], c) : 0;
        }
        __syncthreads();
        for (int i = t; i < 1024; i += 256) s_cnt[i] = s_base[i];
        __syncthreads();

        #pragma unroll
        for (int k = 0; k < 16; ++k) {
            int i = t + k * 256;
            if (i < count) {
                int e = chbase + i;
                int d = dst[e];
                int s = src[e];
                int bkt = d >> LOGB;
                int pos = atomicAdd(&s_cnt[bkt], 1);
                s_stage[pos] = ((unsigned)(d & (BNODES - 1)) << sbits) | (unsigned)s;
                s_addr[pos]  = s_gb[bkt] + (pos - s_base[bkt]);
            }
        }
        __syncthreads();

        #pragma unroll
        for (int k = 0; k < 16; ++k) {
            int i = t + k * 256;
            if (i < count) packed[s_addr[i]] = s_stage[i];
        }
    } else {
        // ---------------- transform body: g = bf16(feat @ W) ----------------
        // ft XOR-swizzled: element (kk, r) stored at kk*64 + (r ^ (kk & 60)).
        // Kills the 16-way staging bank conflict (all kk of one r hit bank r%32
        // unswizzled); float4 reads stay 16B-aligned since kk&60 is a mult of 4.
        float* ft = (float*)smem;            // 64*64 floats
        float* Ws = (float*)(smem + 16384);  // 64*64 floats

        int tid = bid - min(nblk, (bid + R - 1) / R);
        int n0 = tid * TN;

        // zero sentinel row (row n_nodes)
        if (tid == 0 && t < 64) g[(size_t)n_nodes * D + t] = 0;

        {   // stage W, coalesced
            const float4* W4 = (const float4*)W;
            float4* Ws4 = (float4*)Ws;
            #pragma unroll
            for (int i = 0; i < 4; ++i) Ws4[t + i * 256] = W4[t + i * 256];
        }
        {   // stage feat tile transposed + swizzled
            const float4* f4 = (const float4*)feat;
            #pragma unroll
            for (int it = 0; it < 4; ++it) {
                int i = it * 256 + t;
                int r = i >> 4, c = i & 15;
                int node = n0 + r;
                float4 v = (node < n_nodes) ? f4[(size_t)node * 16 + c]
                                            : make_float4(0.f, 0.f, 0.f, 0.f);
                int sw = r ^ (4 * c);        // (4c+j)&60 == 4c for j=0..3
                ft[(4 * c + 0) * 64 + sw] = v.x;
                ft[(4 * c + 1) * 64 + sw] = v.y;
                ft[(4 * c + 2) * 64 + sw] = v.z;
                ft[(4 * c + 3) * 64 + sw] = v.w;
            }
        }
        __syncthreads();

        int nq = t >> 4, cq = t & 15;
        int n4 = nq * 4, c4 = cq * 4;

        float4 a0 = make_float4(0.f, 0.f, 0.f, 0.f);
        float4 a1 = a0, a2 = a0, a3 = a0;

        #pragma unroll 16
        for (int k = 0; k < D; ++k) {
            float4 fv = *reinterpret_cast<const float4*>(&ft[k * 64 + (n4 ^ (k & 60))]);
            float4 wv = *reinterpret_cast<const float4*>(&Ws[k * D + c4]);
            a0.x = fmaf(fv.x, wv.x, a0.x); a0.y = fmaf(fv.x, wv.y, a0.y);
            a0.z = fmaf(fv.x, wv.z, a0.z); a0.w = fmaf(fv.x, wv.w, a0.w);
            a1.x = fmaf(fv.y, wv.x, a1.x); a1.y = fmaf(fv.y, wv.y, a1.y);
            a1.z = fmaf(fv.y, wv.z, a1.z); a1.w = fmaf(fv.y, wv.w, a1.w);
            a2.x = fmaf(fv.z, wv.x, a2.x); a2.y = fmaf(fv.z, wv.y, a2.y);
            a2.z = fmaf(fv.z, wv.z, a2.z); a2.w = fmaf(fv.z, wv.w, a2.w);
            a3.x = fmaf(fv.w, wv.x, a3.x); a3.y = fmaf(fv.w, wv.y, a3.y);
            a3.z = fmaf(fv.w, wv.z, a3.z); a3.w = fmaf(fv.w, wv.w, a3.w);
        }

        float4 accs[4] = {a0, a1, a2, a3};
        #pragma unroll
        for (int i = 0; i < 4; ++i) {
            int node = n0 + n4 + i;
            if (node < n_nodes) {
                ushort4 o;
                o.x = f2bfr(accs[i].x);
                o.y = f2bfr(accs[i].y);
                o.z = f2bfr(accs[i].z);
                o.w = f2bfr(accs[i].w);
                *reinterpret_cast<ushort4*>(g + (size_t)node * D + c4) = o;
            }
        }
    }
}

// ---------------- k_sort128: per-bucket full node sort -> csr2 + noff ----------------

__global__ __launch_bounds__(256) void k_sort128(
    const unsigned* __restrict__ packed,
    const int* __restrict__ bbase,
    int* __restrict__ csr2,
    int* __restrict__ noff,
    int n_nodes, int sbits)
{
    __shared__ int s_cnt[BNODES];
    __shared__ int s_off[BNODES + 1];

    int t = threadIdx.x;
    int b = blockIdx.x;
    int gb = bbase[b], cnt = bbase[b + 1] - gb;

    if (t < BNODES) s_cnt[t] = 0;
    __syncthreads();
    for (int i = t; i < cnt; i += 256)
        atomicAdd(&s_cnt[packed[gb + i] >> sbits], 1);
    __syncthreads();

    if (t < 64) {
        int v0 = s_cnt[2 * t], v1 = s_cnt[2 * t + 1];
        int s = v0 + v1, incl = s;
        #pragma unroll
        for (int o = 1; o < 64; o <<= 1) {
            int u = __shfl_up(incl, o, 64);
            if (t >= o) incl += u;
        }
        int excl = incl - s;
        s_off[2 * t] = excl;
        s_off[2 * t + 1] = excl + v0;
        if (t == 63) s_off[BNODES] = incl;
    }
    __syncthreads();

    if (t <= BNODES) {
        int node = b * BNODES + t;
        if (node <= n_nodes) noff[node] = gb + s_off[t];
    }
    if (t < BNODES) s_cnt[t] = s_off[t];
    __syncthreads();

    unsigned smask = (1u << sbits) - 1u;
    for (int i = t; i < cnt; i += 256) {
        unsigned v = packed[gb + i];
        int pos = atomicAdd(&s_cnt[v >> sbits], 1);
        csr2[gb + pos] = (int)(v & smask);
    }
}

// ---------------- k_bucket6: 32-node blocks over globally-sorted csr2 ----------------

__global__ __launch_bounds__(256) void k_bucket6(
    const ushort* __restrict__ g,      // [(N+1)][64], row N = zeros
    const float* __restrict__ bias,
    const int* __restrict__ noff,      // [N+1]
    const int* __restrict__ csr2,      // [E] srcs sorted by dst
    float* __restrict__ out, int n_nodes)
{
    __shared__ int s_src[CH6];
    __shared__ int s_noff[GRP6 + 1];

    int t = threadIdx.x;
    int n0 = blockIdx.x * GRP6;
    if (t <= GRP6) {
        int node = n0 + t;
        s_noff[t] = noff[node > n_nodes ? n_nodes : node];
    }
    __syncthreads();

    int lane = t & 63, wid = t >> 6;
    int q = lane >> 4;                 // record slot 0..3
    int m = lane & 15;                 // features 4m..4m+3
    const ushort* gm = g + 4 * m;

    float4 acc[8];
    #pragma unroll
    for (int k = 0; k < 8; ++k) acc[k] = make_float4(0.f, 0.f, 0.f, 0.f);

    int beg = s_noff[0], end = s_noff[GRP6];
    for (int cb = beg; cb < end; cb += CH6) {
        int ce = cb + CH6 < end ? cb + CH6 : end;
        __syncthreads();               // protect s_src from previous chunk
        for (int i = cb + t; i < ce; i += 256) s_src[i - cb] = csr2[i];
        __syncthreads();

        #pragma unroll
        for (int k = 0; k < 8; ++k) {
            int r = wid * 8 + k;
            int lo = s_noff[r], hi = s_noff[r + 1];
            if (lo < cb) lo = cb;
            if (hi > ce) hi = ce;
            float4 a = acc[k];
            for (int i = lo; i < hi; i += 16) {
                int i0 = i + q, i1 = i0 + 4, i2 = i0 + 8, i3 = i0 + 12;
                int s0 = (i0 < hi) ? s_src[i0 - cb] : n_nodes;
                int s1 = (i1 < hi) ? s_src[i1 - cb] : n_nodes;
                int s2 = (i2 < hi) ? s_src[i2 - cb] : n_nodes;
                int s3 = (i3 < hi) ? s_src[i3 - cb] : n_nodes;
                uint2 u0 = *reinterpret_cast<const uint2*>(gm + (size_t)s0 * D);
                uint2 u1 = *reinterpret_cast<const uint2*>(gm + (size_t)s1 * D);
                uint2 u2 = *reinterpret_cast<const uint2*>(gm + (size_t)s2 * D);
                uint2 u3 = *reinterpret_cast<const uint2*>(gm + (size_t)s3 * D);
                a.x += blo(u0.x); a.y += bhi(u0.x); a.z += blo(u0.y); a.w += bhi(u0.y);
                a.x += blo(u1.x); a.y += bhi(u1.x); a.z += blo(u1.y); a.w += bhi(u1.y);
                a.x += blo(u2.x); a.y += bhi(u2.x); a.z += blo(u2.y); a.w += bhi(u2.y);
                a.x += blo(u3.x); a.y += bhi(u3.x); a.z += blo(u3.y); a.w += bhi(u3.y);
            }
            acc[k] = a;
        }
    }

    float4 bj = *reinterpret_cast<const float4*>(bias + 4 * m);
    #pragma unroll
    for (int k = 0; k < 8; ++k) {
        float4 v = acc[k];
        v.x += __shfl_xor(v.x, 16, 64);
        v.y += __shfl_xor(v.y, 16, 64);
        v.z += __shfl_xor(v.z, 16, 64);
        v.w += __shfl_xor(v.w, 16, 64);
        v.x += __shfl_xor(v.x, 32, 64);
        v.y += __shfl_xor(v.y, 32, 64);
        v.z += __shfl_xor(v.z, 32, 64);
        v.w += __shfl_xor(v.w, 32, 64);
        if ((k & 3) == q) {
            int r = wid * 8 + k;
            int node = n0 + r;
            if (node < n_nodes) {
                int dgt = s_noff[r + 1] - s_noff[r];
                float4 res;
                if (dgt > 0) {
                    float inv = 1.0f / (float)dgt;
                    res = make_float4(v.x * inv, v.y * inv, v.z * inv, v.w * inv);
                } else {
                    uint2 u = *reinterpret_cast<const uint2*>(gm + (size_t)node * D);
                    res = make_float4(blo(u.x), bhi(u.x), blo(u.y), bhi(u.y));
                }
                res.x = fmaxf(res.x + bj.x, 0.0f);
                res.y = fmaxf(res.y + bj.y, 0.0f);
                res.z = fmaxf(res.z + bj.z, 0.0f);
                res.w = fmaxf(res.w + bj.w, 0.0f);
                *reinterpret_cast<float4*>(out + (size_t)node * D + 4 * m) = res;
            }
        }
    }
}

// ---------------- host ----------------

extern "C" void kernel_launch(void* const* d_in, const int* in_sizes, int n_in,
                              void* d_out, int out_size, void* d_ws, size_t ws_size,
                              hipStream_t stream)
{
    const float* feat = (const float*)d_in[0];
    const int*   src  = (const int*)d_in[1];
    const int*   dst  = (const int*)d_in[2];
    const float* W    = (const float*)d_in[3];
    const float* b    = (const float*)d_in[4];
    float* out = (float*)d_out;

    int n_nodes = in_sizes[0] / D;
    int n_edges = in_sizes[1];
    int nbkt = (n_nodes + BNODES - 1) >> LOGB;

    int sbits = 1;
    while ((1 << sbits) < n_nodes && sbits < 25) sbits++;

    // ws layout: bbase[nbkt+1] | bcnt[nbkt] | bcursor[nbkt] | noff[N+1]
    //            | packed[E] | csr2[E] | g[(N+1)*64] ushort
    size_t base_off   = 0;
    size_t cnt_off    = (((size_t)(nbkt + 1) * 4) + 63) & ~(size_t)63;
    size_t cursor_off = (cnt_off + (size_t)nbkt * 4 + 63) & ~(size_t)63;
    size_t noff_off   = (cursor_off + (size_t)nbkt * 4 + 63) & ~(size_t)63;
    size_t packed_off = (noff_off + ((size_t)n_nodes + 1) * 4 + 63) & ~(size_t)63;
    size_t csr2_off   = (packed_off + (size_t)n_edges * 4 + 63) & ~(size_t)63;
    size_t g_off      = (csr2_off + (size_t)n_edges * 4 + 63) & ~(size_t)63;
    size_t need       = g_off + ((size_t)n_nodes + 1) * D * 2;

    bool ok = (ws_size >= need) && (nbkt <= 1024) && (sbits + LOGB <= 32) &&
              ((1 << sbits) >= n_nodes);
    if (!ok) return;   // cannot happen for this problem's shapes

    char* ws = (char*)d_ws;
    int* bbase   = (int*)(ws + base_off);
    int* bcnt    = (int*)(ws + cnt_off);
    int* bcursor = (int*)(ws + cursor_off);
    int* noff    = (int*)(ws + noff_off);
    unsigned* packed = (unsigned*)(ws + packed_off);
    int* csr2    = (int*)(ws + csr2_off);
    ushort* g    = (ushort*)(ws + g_off);

    int tblk = (n_nodes + TN - 1) / TN;
    int nblk = (n_edges + 4095) / 4096;
    int grid = nblk + tblk;
    int R = grid / nblk;               // interleave stride; >=1 since grid>nblk

    k_zero<<<(nbkt + 255) / 256, 256, 0, stream>>>(bcnt, nbkt);
    k_hist<<<256, 256, 0, stream>>>(dst, bcnt, n_edges, nbkt);
    k_bin_scan<<<1, 1024, 0, stream>>>(bcnt, bbase, bcursor, nbkt);
    k_fused<<<grid, 256, 0, stream>>>(src, dst, bcursor, packed,
                                      n_edges, sbits, nblk, R,
                                      feat, W, g, n_nodes);
    k_sort128<<<nbkt, 256, 0, stream>>>(packed, bbase, csr2, noff,
                                        n_nodes, sbits);
    int ngrp6 = (n_nodes + GRP6 - 1) / GRP6;
    k_bucket6<<<ngrp6, 256, 0, stream>>>(g, b, noff, csr2, out, n_nodes);
}

// Round 15
// 111.144 us; speedup vs baseline: 1.0534x; 1.0534x over previous
//
#include <hip/hip_runtime.h>
#include <hip/hip_bf16.h>

#define D 64
#define LOGB 7            // 128 nodes per bin-bucket
#define BNODES 128
#define GRP6 32           // nodes per k_bucket6 block
#define CH6 1024          // record chunk in k_bucket6
#define TN 64             // nodes per transform block
#define CHS 2048          // edges per scatter block (LDS: 28.3KB < 32KB)

__device__ __forceinline__ float blo(unsigned u) { return __uint_as_float(u << 16); }
__device__ __forceinline__ float bhi(unsigned u) { return __uint_as_float(u & 0xffff0000u); }
__device__ __forceinline__ ushort f2bfr(float x) {
    __hip_bfloat16 hb = __float2bfloat16(x);     // RNE
    return *reinterpret_cast<ushort*>(&hb);
}

// ---------------- k_zero: replaces hipMemsetAsync (fill-path anomaly) ----------------

__global__ __launch_bounds__(256) void k_zero(int* __restrict__ p, int n)
{
    int i = blockIdx.x * 256 + threadIdx.x;
    if (i < n) p[i] = 0;
}

// ---------------- k_hist: standalone dst-bucket histogram ----------------

__global__ __launch_bounds__(256) void k_hist(
    const int* __restrict__ dst, int* __restrict__ cnt, int n_edges, int nbkt)
{
    __shared__ int sc[1024];
    int t = threadIdx.x;
    for (int i = t; i < 1024; i += 256) sc[i] = 0;
    __syncthreads();
    int n4 = n_edges >> 2;
    const int4* d4 = (const int4*)dst;
    int stride = gridDim.x * 256;
    for (int i = blockIdx.x * 256 + t; i < n4; i += stride) {
        int4 d = d4[i];
        atomicAdd(&sc[d.x >> LOGB], 1);
        atomicAdd(&sc[d.y >> LOGB], 1);
        atomicAdd(&sc[d.z >> LOGB], 1);
        atomicAdd(&sc[d.w >> LOGB], 1);
    }
    if (blockIdx.x == 0 && t == 0)
        for (int e = n4 << 2; e < n_edges; ++e) atomicAdd(&cnt[dst[e] >> LOGB], 1);
    __syncthreads();
    for (int i = t; i < nbkt; i += 256) {
        int c = sc[i];
        if (c) atomicAdd(&cnt[i], c);
    }
}

// ---------------- k_bin_scan ----------------

__global__ __launch_bounds__(1024) void k_bin_scan(
    const int* __restrict__ cnt, int* __restrict__ base,
    int* __restrict__ cursor, int nbkt)
{
    int t = threadIdx.x;
    int v = (t < nbkt) ? cnt[t] : 0;
    int lane = t & 63;
    int incl = v;
    #pragma unroll
    for (int o = 1; o < 64; o <<= 1) {
        int u = __shfl_up(incl, o, 64);
        if (lane >= o) incl += u;
    }
    __shared__ int wtot[16];
    if (lane == 63) wtot[t >> 6] = incl;
    __syncthreads();
    int wpre = 0;
    int w = t >> 6;
    for (int i = 0; i < w; ++i) wpre += wtot[i];
    int excl = wpre + incl - v;
    if (t < nbkt) { base[t] = excl; cursor[t] = excl; }
    if (t == nbkt - 1) base[nbkt] = excl + v;
}

// ---------------- k_fused: blocks [0,nblk) = scatter (2048-edge chunks);
//                  [nblk,..) = transform. Sequential split (R13 layout — the
//                  R14 interleave halved occupancy). 32KB LDS -> 5 blocks/CU.

__global__ __launch_bounds__(256) void k_fused(
    // scatter args
    const int* __restrict__ src, const int* __restrict__ dst,
    int* __restrict__ cursor, unsigned* __restrict__ packed,
    int n_edges, int sbits, int nblk,
    // transform args
    const float* __restrict__ feat, const float* __restrict__ W,
    ushort* __restrict__ g, int n_nodes)
{
    __shared__ __align__(16) char smem[32768];
    int t = threadIdx.x;
    int bid = (int)blockIdx.x;

    if (bid < nblk) {
        // ---------------- bin_scatter body (2048-edge chunk) ----------------
        int* s_cnt  = (int*)smem;                       // 1024 ints
        int* s_base = (int*)(smem + 4096);              // 1024 ints
        int* s_gb   = (int*)(smem + 8192);              // 1024 ints
        int* wtot   = (int*)(smem + 12288);             // 4 ints
        unsigned* s_stage = (unsigned*)(smem + 12304);  // 2048 u32
        int* s_addr = (int*)(smem + 20496);             // 2048 ints (ends 28688)

        int chbase = bid * CHS;
        int count = n_edges - chbase;
        if (count > CHS) count = CHS;

        for (int i = t; i < 1024; i += 256) s_cnt[i] = 0;
        __syncthreads();

        #pragma unroll
        for (int k = 0; k < 8; ++k) {
            int i = t + k * 256;
            if (i < count) atomicAdd(&s_cnt[dst[chbase + i] >> LOGB], 1);
        }
        __syncthreads();

        int b4 = t * 4;
        int v0 = s_cnt[b4], v1 = s_cnt[b4 + 1], v2 = s_cnt[b4 + 2], v3 = s_cnt[b4 + 3];
        int ssum = v0 + v1 + v2 + v3;
        int lane = t & 63;
        int incl = ssum;
        #pragma unroll
        for (int o = 1; o < 64; o <<= 1) {
            int u = __shfl_up(incl, o, 64);
            if (lane >= o) incl += u;
        }
        if (lane == 63) wtot[t >> 6] = incl;
        __syncthreads();
        int wpre = 0;
        int w = t >> 6;
        for (int i = 0; i < w; ++i) wpre += wtot[i];
        int excl = wpre + incl - ssum;
        s_base[b4]     = excl;
        s_base[b4 + 1] = excl + v0;
        s_base[b4 + 2] = excl + v0 + v1;
        s_base[b4 + 3] = excl + v0 + v1 + v2;
        __syncthreads();

        for (int i = t; i < 1024; i += 256) {
            int c = s_cnt[i];
            s_gb[i] = c ? atomicAdd(&cursor[i], c) : 0;
        }
        __syncthreads();
        for (int i = t; i < 1024; i += 256) s_cnt[i] = s_base[i];
        __syncthreads();

        #pragma unroll
        for (int k = 0; k < 8; ++k) {
            int i = t + k * 256;
            if (i < count) {
                int e = chbase + i;
                int d = dst[e];
                int s = src[e];
                int bkt = d >> LOGB;
                int pos = atomicAdd(&s_cnt[bkt], 1);
                s_stage[pos] = ((unsigned)(d & (BNODES - 1)) << sbits) | (unsigned)s;
                s_addr[pos]  = s_gb[bkt] + (pos - s_base[bkt]);
            }
        }
        __syncthreads();

        #pragma unroll
        for (int k = 0; k < 8; ++k) {
            int i = t + k * 256;
            if (i < count) packed[s_addr[i]] = s_stage[i];
        }
    } else {
        // ---------------- transform body: g = bf16(feat @ W) ----------------
        // ft XOR-swizzled (kills 16-way staging conflict): element (kk, r) at
        // kk*64 + (r ^ (kk & 60)); float4 reads stay 16B-aligned.
        float* ft = (float*)smem;            // 64*64 floats (16KB)
        float* Ws = (float*)(smem + 16384);  // 64*64 floats (16KB)

        int tid = bid - nblk;
        int n0 = tid * TN;

        // zero sentinel row (row n_nodes)
        if (tid == 0 && t < 64) g[(size_t)n_nodes * D + t] = 0;

        {   // stage W, coalesced
            const float4* W4 = (const float4*)W;
            float4* Ws4 = (float4*)Ws;
            #pragma unroll
            for (int i = 0; i < 4; ++i) Ws4[t + i * 256] = W4[t + i * 256];
        }
        {   // stage feat tile transposed + swizzled
            const float4* f4 = (const float4*)feat;
            #pragma unroll
            for (int it = 0; it < 4; ++it) {
                int i = it * 256 + t;
                int r = i >> 4, c = i & 15;
                int node = n0 + r;
                float4 v = (node < n_nodes) ? f4[(size_t)node * 16 + c]
                                            : make_float4(0.f, 0.f, 0.f, 0.f);
                int sw = r ^ (4 * c);        // (4c+j)&60 == 4c for j=0..3
                ft[(4 * c + 0) * 64 + sw] = v.x;
                ft[(4 * c + 1) * 64 + sw] = v.y;
                ft[(4 * c + 2) * 64 + sw] = v.z;
                ft[(4 * c + 3) * 64 + sw] = v.w;
            }
        }
        __syncthreads();

        int nq = t >> 4, cq = t & 15;
        int n4 = nq * 4, c4 = cq * 4;

        float4 a0 = make_float4(0.f, 0.f, 0.f, 0.f);
        float4 a1 = a0, a2 = a0, a3 = a0;

        #pragma unroll 16
        for (int k = 0; k < D; ++k) {
            float4 fv = *reinterpret_cast<const float4*>(&ft[k * 64 + (n4 ^ (k & 60))]);
            float4 wv = *reinterpret_cast<const float4*>(&Ws[k * D + c4]);
            a0.x = fmaf(fv.x, wv.x, a0.x); a0.y = fmaf(fv.x, wv.y, a0.y);
            a0.z = fmaf(fv.x, wv.z, a0.z); a0.w = fmaf(fv.x, wv.w, a0.w);
            a1.x = fmaf(fv.y, wv.x, a1.x); a1.y = fmaf(fv.y, wv.y, a1.y);
            a1.z = fmaf(fv.y, wv.z, a1.z); a1.w = fmaf(fv.y, wv.w, a1.w);
            a2.x = fmaf(fv.z, wv.x, a2.x); a2.y = fmaf(fv.z, wv.y, a2.y);
            a2.z = fmaf(fv.z, wv.z, a2.z); a2.w = fmaf(fv.z, wv.w, a2.w);
            a3.x = fmaf(fv.w, wv.x, a3.x); a3.y = fmaf(fv.w, wv.y, a3.y);
            a3.z = fmaf(fv.w, wv.z, a3.z); a3.w = fmaf(fv.w, wv.w, a3.w);
        }

        float4 accs[4] = {a0, a1, a2, a3};
        #pragma unroll
        for (int i = 0; i < 4; ++i) {
            int node = n0 + n4 + i;
            if (node < n_nodes) {
                ushort4 o;
                o.x = f2bfr(accs[i].x);
                o.y = f2bfr(accs[i].y);
                o.z = f2bfr(accs[i].z);
                o.w = f2bfr(accs[i].w);
                *reinterpret_cast<ushort4*>(g + (size_t)node * D + c4) = o;
            }
        }
    }
}

// ---------------- k_sort128: per-bucket full node sort -> csr2 + noff ----------------

__global__ __launch_bounds__(256) void k_sort128(
    const unsigned* __restrict__ packed,
    const int* __restrict__ bbase,
    int* __restrict__ csr2,
    int* __restrict__ noff,
    int n_nodes, int sbits)
{
    __shared__ int s_cnt[BNODES];
    __shared__ int s_off[BNODES + 1];

    int t = threadIdx.x;
    int b = blockIdx.x;
    int gb = bbase[b], cnt = bbase[b + 1] - gb;

    if (t < BNODES) s_cnt[t] = 0;
    __syncthreads();
    for (int i = t; i < cnt; i += 256)
        atomicAdd(&s_cnt[packed[gb + i] >> sbits], 1);
    __syncthreads();

    if (t < 64) {
        int v0 = s_cnt[2 * t], v1 = s_cnt[2 * t + 1];
        int s = v0 + v1, incl = s;
        #pragma unroll
        for (int o = 1; o < 64; o <<= 1) {
            int u = __shfl_up(incl, o, 64);
            if (t >= o) incl += u;
        }
        int excl = incl - s;
        s_off[2 * t] = excl;
        s_off[2 * t + 1] = excl + v0;
        if (t == 63) s_off[BNODES] = incl;
    }
    __syncthreads();

    if (t <= BNODES) {
        int node = b * BNODES + t;
        if (node <= n_nodes) noff[node] = gb + s_off[t];
    }
    if (t < BNODES) s_cnt[t] = s_off[t];
    __syncthreads();

    unsigned smask = (1u << sbits) - 1u;
    for (int i = t; i < cnt; i += 256) {
        unsigned v = packed[gb + i];
        int pos = atomicAdd(&s_cnt[v >> sbits], 1);
        csr2[gb + pos] = (int)(v & smask);
    }
}

// ---------------- k_bucket6: 32-node blocks over globally-sorted csr2 ----------------

__global__ __launch_bounds__(256) void k_bucket6(
    const ushort* __restrict__ g,      // [(N+1)][64], row N = zeros
    const float* __restrict__ bias,
    const int* __restrict__ noff,      // [N+1]
    const int* __restrict__ csr2,      // [E] srcs sorted by dst
    float* __restrict__ out, int n_nodes)
{
    __shared__ int s_src[CH6];
    __shared__ int s_noff[GRP6 + 1];

    int t = threadIdx.x;
    int n0 = blockIdx.x * GRP6;
    if (t <= GRP6) {
        int node = n0 + t;
        s_noff[t] = noff[node > n_nodes ? n_nodes : node];
    }
    __syncthreads();

    int lane = t & 63, wid = t >> 6;
    int q = lane >> 4;                 // record slot 0..3
    int m = lane & 15;                 // features 4m..4m+3
    const ushort* gm = g + 4 * m;

    float4 acc[8];
    #pragma unroll
    for (int k = 0; k < 8; ++k) acc[k] = make_float4(0.f, 0.f, 0.f, 0.f);

    int beg = s_noff[0], end = s_noff[GRP6];
    for (int cb = beg; cb < end; cb += CH6) {
        int ce = cb + CH6 < end ? cb + CH6 : end;
        __syncthreads();               // protect s_src from previous chunk
        for (int i = cb + t; i < ce; i += 256) s_src[i - cb] = csr2[i];
        __syncthreads();

        #pragma unroll
        for (int k = 0; k < 8; ++k) {
            int r = wid * 8 + k;
            int lo = s_noff[r], hi = s_noff[r + 1];
            if (lo < cb) lo = cb;
            if (hi > ce) hi = ce;
            float4 a = acc[k];
            for (int i = lo; i < hi; i += 16) {
                int i0 = i + q, i1 = i0 + 4, i2 = i0 + 8, i3 = i0 + 12;
                int s0 = (i0 < hi) ? s_src[i0 - cb] : n_nodes;
                int s1 = (i1 < hi) ? s_src[i1 - cb] : n_nodes;
                int s2 = (i2 < hi) ? s_src[i2 - cb] : n_nodes;
                int s3 = (i3 < hi) ? s_src[i3 - cb] : n_nodes;
                uint2 u0 = *reinterpret_cast<const uint2*>(gm + (size_t)s0 * D);
                uint2 u1 = *reinterpret_cast<const uint2*>(gm + (size_t)s1 * D);
                uint2 u2 = *reinterpret_cast<const uint2*>(gm + (size_t)s2 * D);
                uint2 u3 = *reinterpret_cast<const uint2*>(gm + (size_t)s3 * D);
                a.x += blo(u0.x); a.y += bhi(u0.x); a.z += blo(u0.y); a.w += bhi(u0.y);
                a.x += blo(u1.x); a.y += bhi(u1.x); a.z += blo(u1.y); a.w += bhi(u1.y);
                a.x += blo(u2.x); a.y += bhi(u2.x); a.z += blo(u2.y); a.w += bhi(u2.y);
                a.x += blo(u3.x); a.y += bhi(u3.x); a.z += blo(u3.y); a.w += bhi(u3.y);
            }
            acc[k] = a;
        }
    }

    float4 bj = *reinterpret_cast<const float4*>(bias + 4 * m);
    #pragma unroll
    for (int k = 0; k < 8; ++k) {
        float4 v = acc[k];
        v.x += __shfl_xor(v.x, 16, 64);
        v.y += __shfl_xor(v.y, 16, 64);
        v.z += __shfl_xor(v.z, 16, 64);
        v.w += __shfl_xor(v.w, 16, 64);
        v.x += __shfl_xor(v.x, 32, 64);
        v.y += __shfl_xor(v.y, 32, 64);
        v.z += __shfl_xor(v.z, 32, 64);
        v.w += __shfl_xor(v.w, 32, 64);
        if ((k & 3) == q) {
            int r = wid * 8 + k;
            int node = n0 + r;
            if (node < n_nodes) {
                int dgt = s_noff[r + 1] - s_noff[r];
                float4 res;
                if (dgt > 0) {
                    float inv = 1.0f / (float)dgt;
                    res = make_float4(v.x * inv, v.y * inv, v.z * inv, v.w * inv);
                } else {
                    uint2 u = *reinterpret_cast<const uint2*>(gm + (size_t)node * D);
                    res = make_float4(blo(u.x), bhi(u.x), blo(u.y), bhi(u.y));
                }
                res.x = fmaxf(res.x + bj.x, 0.0f);
                res.y = fmaxf(res.y + bj.y, 0.0f);
                res.z = fmaxf(res.z + bj.z, 0.0f);
                res.w = fmaxf(res.w + bj.w, 0.0f);
                *reinterpret_cast<float4*>(out + (size_t)node * D + 4 * m) = res;
            }
        }
    }
}

// ---------------- host ----------------

extern "C" void kernel_launch(void* const* d_in, const int* in_sizes, int n_in,
                              void* d_out, int out_size, void* d_ws, size_t ws_size,
                              hipStream_t stream)
{
    const float* feat = (const float*)d_in[0];
    const int*   src  = (const int*)d_in[1];
    const int*   dst  = (const int*)d_in[2];
    const float* W    = (const float*)d_in[3];
    const float* b    = (const float*)d_in[4];
    float* out = (float*)d_out;

    int n_nodes = in_sizes[0] / D;
    int n_edges = in_sizes[1];
    int nbkt = (n_nodes + BNODES - 1) >> LOGB;

    int sbits = 1;
    while ((1 << sbits) < n_nodes && sbits < 25) sbits++;

    // ws layout: bbase[nbkt+1] | bcnt[nbkt] | bcursor[nbkt] | noff[N+1]
    //            | packed[E] | csr2[E] | g[(N+1)*64] ushort
    size_t base_off   = 0;
    size_t cnt_off    = (((size_t)(nbkt + 1) * 4) + 63) & ~(size_t)63;
    size_t cursor_off = (cnt_off + (size_t)nbkt * 4 + 63) & ~(size_t)63;
    size_t noff_off   = (cursor_off + (size_t)nbkt * 4 + 63) & ~(size_t)63;
    size_t packed_off = (noff_off + ((size_t)n_nodes + 1) * 4 + 63) & ~(size_t)63;
    size_t csr2_off   = (packed_off + (size_t)n_edges * 4 + 63) & ~(size_t)63;
    size_t g_off      = (csr2_off + (size_t)n_edges * 4 + 63) & ~(size_t)63;
    size_t need       = g_off + ((size_t)n_nodes + 1) * D * 2;

    bool ok = (ws_size >= need) && (nbkt <= 1024) && (sbits + LOGB <= 32) &&
              ((1 << sbits) >= n_nodes);
    if (!ok) return;   // cannot happen for this problem's shapes

    char* ws = (char*)d_ws;
    int* bbase   = (int*)(ws + base_off);
    int* bcnt    = (int*)(ws + cnt_off);
    int* bcursor = (int*)(ws + cursor_off);
    int* noff    = (int*)(ws + noff_off);
    unsigned* packed = (unsigned*)(ws + packed_off);
    int* csr2    = (int*)(ws + csr2_off);
    ushort* g    = (ushort*)(ws + g_off);

    int tblk = (n_nodes + TN - 1) / TN;
    int nblk = (n_edges + CHS - 1) / CHS;

    k_zero<<<(nbkt + 255) / 256, 256, 0, stream>>>(bcnt, nbkt);
    k_hist<<<256, 256, 0, stream>>>(dst, bcnt, n_edges, nbkt);
    k_bin_scan<<<1, 1024, 0, stream>>>(bcnt, bbase, bcursor, nbkt);
    k_fused<<<nblk + tblk, 256, 0, stream>>>(src, dst, bcursor, packed,
                                             n_edges, sbits, nblk,
                                             feat, W, g, n_nodes);
    k_sort128<<<nbkt, 256, 0, stream>>>(packed, bbase, csr2, noff,
                                        n_nodes, sbits);
    int ngrp6 = (n_nodes + GRP6 - 1) / GRP6;
    k_bucket6<<<ngrp6, 256, 0, stream>>>(g, b, noff, csr2, out, n_nodes);
}

// Round 16
// 97.297 us; speedup vs baseline: 1.2033x; 1.1423x over previous
//
#include <hip/hip_runtime.h>
#include <hip/hip_bf16.h>

#define D 64
#define LOGB 7            // 128 nodes per bin-bucket
#define BNODES 128
#define GRP6 32           // nodes per k_bucket6 block
#define CH6 1024          // record chunk in k_bucket6
#define TN 64             // nodes per transform block
#define CHS 4096          // edges per scatter block

__device__ __forceinline__ float blo(unsigned u) { return __uint_as_float(u << 16); }
__device__ __forceinline__ float bhi(unsigned u) { return __uint_as_float(u & 0xffff0000u); }
__device__ __forceinline__ ushort f2bfr(float x) {
    __hip_bfloat16 hb = __float2bfloat16(x);     // RNE
    return *reinterpret_cast<ushort*>(&hb);
}

// ---------------- k_zero ----------------

__global__ __launch_bounds__(256) void k_zero(int* __restrict__ p, int n)
{
    int i = blockIdx.x * 256 + threadIdx.x;
    if (i < n) p[i] = 0;
}

// ---------------- k_hist: dst-bucket histogram ----------------

__global__ __launch_bounds__(256) void k_hist(
    const int* __restrict__ dst, int* __restrict__ cnt, int n_edges, int nbkt)
{
    __shared__ int sc[1024];
    int t = threadIdx.x;
    for (int i = t; i < 1024; i += 256) sc[i] = 0;
    __syncthreads();
    int n4 = n_edges >> 2;
    const int4* d4 = (const int4*)dst;
    int stride = gridDim.x * 256;
    for (int i = blockIdx.x * 256 + t; i < n4; i += stride) {
        int4 d = d4[i];
        atomicAdd(&sc[d.x >> LOGB], 1);
        atomicAdd(&sc[d.y >> LOGB], 1);
        atomicAdd(&sc[d.z >> LOGB], 1);
        atomicAdd(&sc[d.w >> LOGB], 1);
    }
    if (blockIdx.x == 0 && t == 0)
        for (int e = n4 << 2; e < n_edges; ++e) atomicAdd(&cnt[dst[e] >> LOGB], 1);
    __syncthreads();
    for (int i = t; i < nbkt; i += 256) {
        int c = sc[i];
        if (c) atomicAdd(&cnt[i], c);
    }
}

// ---------------- k_bin_scan ----------------

__global__ __launch_bounds__(1024) void k_bin_scan(
    const int* __restrict__ cnt, int* __restrict__ base,
    int* __restrict__ cursor, int nbkt)
{
    int t = threadIdx.x;
    int v = (t < nbkt) ? cnt[t] : 0;
    int lane = t & 63;
    int incl = v;
    #pragma unroll
    for (int o = 1; o < 64; o <<= 1) {
        int u = __shfl_up(incl, o, 64);
        if (lane >= o) incl += u;
    }
    __shared__ int wtot[16];
    if (lane == 63) wtot[t >> 6] = incl;
    __syncthreads();
    int wpre = 0;
    int w = t >> 6;
    for (int i = 0; i < w; ++i) wpre += wtot[i];
    int excl = wpre + incl - v;
    if (t < nbkt) { base[t] = excl; cursor[t] = excl; }
    if (t == nbkt - 1) base[nbkt] = excl + v;
}

// ---------------- k_fused: blocks [0,nblk) = scatter (4096-edge chunks);
//   [nblk,..) = transform. Sequential split. Scatter write-out pass is
//   bucket-owned (no s_addr) -> LDS 28KB; smem = 32KB -> 5 blocks/CU.

__global__ __launch_bounds__(256) void k_fused(
    // scatter args
    const int* __restrict__ src, const int* __restrict__ dst,
    int* __restrict__ cursor, unsigned* __restrict__ packed,
    int n_edges, int sbits, int nblk,
    // transform args
    const float* __restrict__ feat, const float* __restrict__ W,
    ushort* __restrict__ g, int n_nodes)
{
    __shared__ __align__(16) char smem[32768];
    int t = threadIdx.x;
    int bid = (int)blockIdx.x;

    if (bid < nblk) {
        // ---------------- bin_scatter body (4096-edge chunk) ----------------
        int* s_cnt  = (int*)smem;                       // 1024 ints
        int* s_base = (int*)(smem + 4096);              // 1024 ints
        int* s_gb   = (int*)(smem + 8192);              // 1024 ints
        int* wtot   = (int*)(smem + 12288);             // 4 ints
        unsigned* s_stage = (unsigned*)(smem + 12304);  // 4096 u32 (ends 28688)

        int chbase = bid * CHS;
        int count = n_edges - chbase;
        if (count > CHS) count = CHS;

        for (int i = t; i < 1024; i += 256) s_cnt[i] = 0;
        __syncthreads();

        #pragma unroll
        for (int k = 0; k < 16; ++k) {
            int i = t + k * 256;
            if (i < count) atomicAdd(&s_cnt[dst[chbase + i] >> LOGB], 1);
        }
        __syncthreads();

        int b4 = t * 4;
        int v0 = s_cnt[b4], v1 = s_cnt[b4 + 1], v2 = s_cnt[b4 + 2], v3 = s_cnt[b4 + 3];
        int ssum = v0 + v1 + v2 + v3;
        int lane = t & 63;
        int incl = ssum;
        #pragma unroll
        for (int o = 1; o < 64; o <<= 1) {
            int u = __shfl_up(incl, o, 64);
            if (lane >= o) incl += u;
        }
        if (lane == 63) wtot[t >> 6] = incl;
        __syncthreads();
        int wpre = 0;
        int w = t >> 6;
        for (int i = 0; i < w; ++i) wpre += wtot[i];
        int excl = wpre + incl - ssum;
        s_base[b4]     = excl;
        s_base[b4 + 1] = excl + v0;
        s_base[b4 + 2] = excl + v0 + v1;
        s_base[b4 + 3] = excl + v0 + v1 + v2;
        __syncthreads();

        for (int i = t; i < 1024; i += 256) {
            int c = s_cnt[i];
            s_gb[i] = c ? atomicAdd(&cursor[i], c) : 0;
        }
        __syncthreads();
        for (int i = t; i < 1024; i += 256) s_cnt[i] = s_base[i];
        __syncthreads();

        // pass 2: scatter records into bucket-sorted LDS order
        #pragma unroll
        for (int k = 0; k < 16; ++k) {
            int i = t + k * 256;
            if (i < count) {
                int e = chbase + i;
                int d = dst[e];
                int s = src[e];
                int bkt = d >> LOGB;
                int pos = atomicAdd(&s_cnt[bkt], 1);
                s_stage[pos] = ((unsigned)(d & (BNODES - 1)) << sbits) | (unsigned)s;
            }
        }
        __syncthreads();

        // pass 3: bucket-owned write-out — thread t owns buckets 4t..4t+3;
        // each bucket's segment is written to ascending global addresses.
        #pragma unroll
        for (int bb = 0; bb < 4; ++bb) {
            int bkt = b4 + bb;
            int lo = s_base[bkt], hi = s_cnt[bkt];   // s_cnt = end after pass 2
            int gbo = s_gb[bkt];
            for (int i = lo; i < hi; ++i)
                packed[gbo + (i - lo)] = s_stage[i];
        }
    } else {
        // ---------------- transform body: g = bf16(feat @ W) ----------------
        // ft XOR-swizzled (16-way staging conflict fix): (kk, r) stored at
        // kk*64 + (r ^ (kk & 60)); float4 reads stay 16B-aligned.
        float* ft = (float*)smem;            // 64*64 floats (16KB)
        float* Ws = (float*)(smem + 16384);  // 64*64 floats (16KB)

        int tid = bid - nblk;
        int n0 = tid * TN;

        // zero sentinel row (row n_nodes)
        if (tid == 0 && t < 64) g[(size_t)n_nodes * D + t] = 0;

        {   // stage W, coalesced
            const float4* W4 = (const float4*)W;
            float4* Ws4 = (float4*)Ws;
            #pragma unroll
            for (int i = 0; i < 4; ++i) Ws4[t + i * 256] = W4[t + i * 256];
        }
        {   // stage feat tile transposed + swizzled
            const float4* f4 = (const float4*)feat;
            #pragma unroll
            for (int it = 0; it < 4; ++it) {
                int i = it * 256 + t;
                int r = i >> 4, c = i & 15;
                int node = n0 + r;
                float4 v = (node < n_nodes) ? f4[(size_t)node * 16 + c]
                                            : make_float4(0.f, 0.f, 0.f, 0.f);
                int sw = r ^ (4 * c);        // (4c+j)&60 == 4c for j=0..3
                ft[(4 * c + 0) * 64 + sw] = v.x;
                ft[(4 * c + 1) * 64 + sw] = v.y;
                ft[(4 * c + 2) * 64 + sw] = v.z;
                ft[(4 * c + 3) * 64 + sw] = v.w;
            }
        }
        __syncthreads();

        int nq = t >> 4, cq = t & 15;
        int n4 = nq * 4, c4 = cq * 4;

        float4 a0 = make_float4(0.f, 0.f, 0.f, 0.f);
        float4 a1 = a0, a2 = a0, a3 = a0;

        #pragma unroll 16
        for (int k = 0; k < D; ++k) {
            float4 fv = *reinterpret_cast<const float4*>(&ft[k * 64 + (n4 ^ (k & 60))]);
            float4 wv = *reinterpret_cast<const float4*>(&Ws[k * D + c4]);
            a0.x = fmaf(fv.x, wv.x, a0.x); a0.y = fmaf(fv.x, wv.y, a0.y);
            a0.z = fmaf(fv.x, wv.z, a0.z); a0.w = fmaf(fv.x, wv.w, a0.w);
            a1.x = fmaf(fv.y, wv.x, a1.x); a1.y = fmaf(fv.y, wv.y, a1.y);
            a1.z = fmaf(fv.y, wv.z, a1.z); a1.w = fmaf(fv.y, wv.w, a1.w);
            a2.x = fmaf(fv.z, wv.x, a2.x); a2.y = fmaf(fv.z, wv.y, a2.y);
            a2.z = fmaf(fv.z, wv.z, a2.z); a2.w = fmaf(fv.z, wv.w, a2.w);
            a3.x = fmaf(fv.w, wv.x, a3.x); a3.y = fmaf(fv.w, wv.y, a3.y);
            a3.z = fmaf(fv.w, wv.z, a3.z); a3.w = fmaf(fv.w, wv.w, a3.w);
        }

        float4 accs[4] = {a0, a1, a2, a3};
        #pragma unroll
        for (int i = 0; i < 4; ++i) {
            int node = n0 + n4 + i;
            if (node < n_nodes) {
                ushort4 o;
                o.x = f2bfr(accs[i].x);
                o.y = f2bfr(accs[i].y);
                o.z = f2bfr(accs[i].z);
                o.w = f2bfr(accs[i].w);
                *reinterpret_cast<ushort4*>(g + (size_t)node * D + c4) = o;
            }
        }
    }
}

// ---------------- k_sort128: per-bucket full node sort -> csr2 + noff ----------------

__global__ __launch_bounds__(256) void k_sort128(
    const unsigned* __restrict__ packed,
    const int* __restrict__ bbase,
    int* __restrict__ csr2,
    int* __restrict__ noff,
    int n_nodes, int sbits)
{
    __shared__ int s_cnt[BNODES];
    __shared__ int s_off[BNODES + 1];

    int t = threadIdx.x;
    int b = blockIdx.x;
    int gb = bbase[b], cnt = bbase[b + 1] - gb;

    if (t < BNODES) s_cnt[t] = 0;
    __syncthreads();
    for (int i = t; i < cnt; i += 256)
        atomicAdd(&s_cnt[packed[gb + i] >> sbits], 1);
    __syncthreads();

    if (t < 64) {
        int v0 = s_cnt[2 * t], v1 = s_cnt[2 * t + 1];
        int s = v0 + v1, incl = s;
        #pragma unroll
        for (int o = 1; o < 64; o <<= 1) {
            int u = __shfl_up(incl, o, 64);
            if (t >= o) incl += u;
        }
        int excl = incl - s;
        s_off[2 * t] = excl;
        s_off[2 * t + 1] = excl + v0;
        if (t == 63) s_off[BNODES] = incl;
    }
    __syncthreads();

    if (t <= BNODES) {
        int node = b * BNODES + t;
        if (node <= n_nodes) noff[node] = gb + s_off[t];
    }
    if (t < BNODES) s_cnt[t] = s_off[t];
    __syncthreads();

    unsigned smask = (1u << sbits) - 1u;
    for (int i = t; i < cnt; i += 256) {
        unsigned v = packed[gb + i];
        int pos = atomicAdd(&s_cnt[v >> sbits], 1);
        csr2[gb + pos] = (int)(v & smask);
    }
}

// ---------------- k_bucket6: 32-node blocks over globally-sorted csr2 ----------------

__global__ __launch_bounds__(256) void k_bucket6(
    const ushort* __restrict__ g,      // [(N+1)][64], row N = zeros
    const float* __restrict__ bias,
    const int* __restrict__ noff,      // [N+1]
    const int* __restrict__ csr2,      // [E] srcs sorted by dst
    float* __restrict__ out, int n_nodes)
{
    __shared__ int s_src[CH6];
    __shared__ int s_noff[GRP6 + 1];

    int t = threadIdx.x;
    int n0 = blockIdx.x * GRP6;
    if (t <= GRP6) {
        int node = n0 + t;
        s_noff[t] = noff[node > n_nodes ? n_nodes : node];
    }
    __syncthreads();

    int lane = t & 63, wid = t >> 6;
    int q = lane >> 4;                 // record slot 0..3
    int m = lane & 15;                 // features 4m..4m+3
    const ushort* gm = g + 4 * m;

    float4 acc[8];
    #pragma unroll
    for (int k = 0; k < 8; ++k) acc[k] = make_float4(0.f, 0.f, 0.f, 0.f);

    int beg = s_noff[0], end = s_noff[GRP6];
    for (int cb = beg; cb < end; cb += CH6) {
        int ce = cb + CH6 < end ? cb + CH6 : end;
        __syncthreads();               // protect s_src from previous chunk
        for (int i = cb + t; i < ce; i += 256) s_src[i - cb] = csr2[i];
        __syncthreads();

        #pragma unroll
        for (int k = 0; k < 8; ++k) {
            int r = wid * 8 + k;
            int lo = s_noff[r], hi = s_noff[r + 1];
            if (lo < cb) lo = cb;
            if (hi > ce) hi = ce;
            float4 a = acc[k];
            for (int i = lo; i < hi; i += 16) {
                int i0 = i + q, i1 = i0 + 4, i2 = i0 + 8, i3 = i0 + 12;
                int s0 = (i0 < hi) ? s_src[i0 - cb] : n_nodes;
                int s1 = (i1 < hi) ? s_src[i1 - cb] : n_nodes;
                int s2 = (i2 < hi) ? s_src[i2 - cb] : n_nodes;
                int s3 = (i3 < hi) ? s_src[i3 - cb] : n_nodes;
                uint2 u0 = *reinterpret_cast<const uint2*>(gm + (size_t)s0 * D);
                uint2 u1 = *reinterpret_cast<const uint2*>(gm + (size_t)s1 * D);
                uint2 u2 = *reinterpret_cast<const uint2*>(gm + (size_t)s2 * D);
                uint2 u3 = *reinterpret_cast<const uint2*>(gm + (size_t)s3 * D);
                a.x += blo(u0.x); a.y += bhi(u0.x); a.z += blo(u0.y); a.w += bhi(u0.y);
                a.x += blo(u1.x); a.y += bhi(u1.x); a.z += blo(u1.y); a.w += bhi(u1.y);
                a.x += blo(u2.x); a.y += bhi(u2.x); a.z += blo(u2.y); a.w += bhi(u2.y);
                a.x += blo(u3.x); a.y += bhi(u3.x); a.z += blo(u3.y); a.w += bhi(u3.y);
            }
            acc[k] = a;
        }
    }

    float4 bj = *reinterpret_cast<const float4*>(bias + 4 * m);
    #pragma unroll
    for (int k = 0; k < 8; ++k) {
        float4 v = acc[k];
        v.x += __shfl_xor(v.x, 16, 64);
        v.y += __shfl_xor(v.y, 16, 64);
        v.z += __shfl_xor(v.z, 16, 64);
        v.w += __shfl_xor(v.w, 16, 64);
        v.x += __shfl_xor(v.x, 32, 64);
        v.y += __shfl_xor(v.y, 32, 64);
        v.z += __shfl_xor(v.z, 32, 64);
        v.w += __shfl_xor(v.w, 32, 64);
        if ((k & 3) == q) {
            int r = wid * 8 + k;
            int node = n0 + r;
            if (node < n_nodes) {
                int dgt = s_noff[r + 1] - s_noff[r];
                float4 res;
                if (dgt > 0) {
                    float inv = 1.0f / (float)dgt;
                    res = make_float4(v.x * inv, v.y * inv, v.z * inv, v.w * inv);
                } else {
                    uint2 u = *reinterpret_cast<const uint2*>(gm + (size_t)node * D);
                    res = make_float4(blo(u.x), bhi(u.x), blo(u.y), bhi(u.y));
                }
                res.x = fmaxf(res.x + bj.x, 0.0f);
                res.y = fmaxf(res.y + bj.y, 0.0f);
                res.z = fmaxf(res.z + bj.z, 0.0f);
                res.w = fmaxf(res.w + bj.w, 0.0f);
                *reinterpret_cast<float4*>(out + (size_t)node * D + 4 * m) = res;
            }
        }
    }
}

// ---------------- host ----------------

extern "C" void kernel_launch(void* const* d_in, const int* in_sizes, int n_in,
                              void* d_out, int out_size, void* d_ws, size_t ws_size,
                              hipStream_t stream)
{
    const float* feat = (const float*)d_in[0];
    const int*   src  = (const int*)d_in[1];
    const int*   dst  = (const int*)d_in[2];
    const float* W    = (const float*)d_in[3];
    const float* b    = (const float*)d_in[4];
    float* out = (float*)d_out;

    int n_nodes = in_sizes[0] / D;
    int n_edges = in_sizes[1];
    int nbkt = (n_nodes + BNODES - 1) >> LOGB;

    int sbits = 1;
    while ((1 << sbits) < n_nodes && sbits < 25) sbits++;

    // ws layout: bbase[nbkt+1] | bcnt[nbkt] | bcursor[nbkt] | noff[N+1]
    //            | packed[E] | csr2[E] | g[(N+1)*64] ushort
    size_t base_off   = 0;
    size_t cnt_off    = (((size_t)(nbkt + 1) * 4) + 63) & ~(size_t)63;
    size_t cursor_off = (cnt_off + (size_t)nbkt * 4 + 63) & ~(size_t)63;
    size_t noff_off   = (cursor_off + (size_t)nbkt * 4 + 63) & ~(size_t)63;
    size_t packed_off = (noff_off + ((size_t)n_nodes + 1) * 4 + 63) & ~(size_t)63;
    size_t csr2_off   = (packed_off + (size_t)n_edges * 4 + 63) & ~(size_t)63;
    size_t g_off      = (csr2_off + (size_t)n_edges * 4 + 63) & ~(size_t)63;
    size_t need       = g_off + ((size_t)n_nodes + 1) * D * 2;

    bool ok = (ws_size >= need) && (nbkt <= 1024) && (sbits + LOGB <= 32) &&
              ((1 << sbits) >= n_nodes);
    if (!ok) return;   // cannot happen for this problem's shapes

    char* ws = (char*)d_ws;
    int* bbase   = (int*)(ws + base_off);
    int* bcnt    = (int*)(ws + cnt_off);
    int* bcursor = (int*)(ws + cursor_off);
    int* noff    = (int*)(ws + noff_off);
    unsigned* packed = (unsigned*)(ws + packed_off);
    int* csr2    = (int*)(ws + csr2_off);
    ushort* g    = (ushort*)(ws + g_off);

    int tblk = (n_nodes + TN - 1) / TN;
    int nblk = (n_edges + CHS - 1) / CHS;

    k_zero<<<(nbkt + 255) / 256, 256, 0, stream>>>(bcnt, nbkt);
    k_hist<<<256, 256, 0, stream>>>(dst, bcnt, n_edges, nbkt);
    k_bin_scan<<<1, 1024, 0, stream>>>(bcnt, bbase, bcursor, nbkt);
    k_fused<<<nblk + tblk, 256, 0, stream>>>(src, dst, bcursor, packed,
                                             n_edges, sbits, nblk,
                                             feat, W, g, n_nodes);
    k_sort128<<<nbkt, 256, 0, stream>>>(packed, bbase, csr2, noff,
                                        n_nodes, sbits);
    int ngrp6 = (n_nodes + GRP6 - 1) / GRP6;
    k_bucket6<<<ngrp6, 256, 0, stream>>>(g, b, noff, csr2, out, n_nodes);
}

// Round 17
// 93.046 us; speedup vs baseline: 1.2583x; 1.0457x over previous
//
#include <hip/hip_runtime.h>
#include <hip/hip_bf16.h>

#define D 64
#define LOGB 7            // 128 nodes per bin-bucket
#define BNODES 128
#define GRP6 32           // nodes per k_bucket6 block
#define CH6 1024          // record chunk in k_bucket6
#define TN 64             // nodes per transform block
#define CHS 4096          // edges per scatter block

__device__ __forceinline__ float blo(unsigned u) { return __uint_as_float(u << 16); }
__device__ __forceinline__ float bhi(unsigned u) { return __uint_as_float(u & 0xffff0000u); }
__device__ __forceinline__ ushort f2bfr(float x) {
    __hip_bfloat16 hb = __float2bfloat16(x);     // RNE
    return *reinterpret_cast<ushort*>(&hb);
}

// ---------------- k_zero ----------------

__global__ __launch_bounds__(256) void k_zero(int* __restrict__ p, int n)
{
    int i = blockIdx.x * 256 + threadIdx.x;
    if (i < n) p[i] = 0;
}

// ---------------- k_hist: dst-bucket histogram ----------------

__global__ __launch_bounds__(256) void k_hist(
    const int* __restrict__ dst, int* __restrict__ cnt, int n_edges, int nbkt)
{
    __shared__ int sc[1024];
    int t = threadIdx.x;
    for (int i = t; i < 1024; i += 256) sc[i] = 0;
    __syncthreads();
    int n4 = n_edges >> 2;
    const int4* d4 = (const int4*)dst;
    int stride = gridDim.x * 256;
    for (int i = blockIdx.x * 256 + t; i < n4; i += stride) {
        int4 d = d4[i];
        atomicAdd(&sc[d.x >> LOGB], 1);
        atomicAdd(&sc[d.y >> LOGB], 1);
        atomicAdd(&sc[d.z >> LOGB], 1);
        atomicAdd(&sc[d.w >> LOGB], 1);
    }
    if (blockIdx.x == 0 && t == 0)
        for (int e = n4 << 2; e < n_edges; ++e) atomicAdd(&cnt[dst[e] >> LOGB], 1);
    __syncthreads();
    for (int i = t; i < nbkt; i += 256) {
        int c = sc[i];
        if (c) atomicAdd(&cnt[i], c);
    }
}

// ---------------- k_bin_scan ----------------

__global__ __launch_bounds__(1024) void k_bin_scan(
    const int* __restrict__ cnt, int* __restrict__ base,
    int* __restrict__ cursor, int nbkt)
{
    int t = threadIdx.x;
    int v = (t < nbkt) ? cnt[t] : 0;
    int lane = t & 63;
    int incl = v;
    #pragma unroll
    for (int o = 1; o < 64; o <<= 1) {
        int u = __shfl_up(incl, o, 64);
        if (lane >= o) incl += u;
    }
    __shared__ int wtot[16];
    if (lane == 63) wtot[t >> 6] = incl;
    __syncthreads();
    int wpre = 0;
    int w = t >> 6;
    for (int i = 0; i < w; ++i) wpre += wtot[i];
    int excl = wpre + incl - v;
    if (t < nbkt) { base[t] = excl; cursor[t] = excl; }
    if (t == nbkt - 1) base[nbkt] = excl + v;
}

// ---------------- k_fused: blocks [0,nblk) = scatter; [nblk,..) = transform.
//   Scatter fast path (full chunks): dst/src loaded ONCE as 4x int4/thread into
//   registers, reused across hist + scatter passes. LDS 28KB -> 5 blocks/CU.

__global__ __launch_bounds__(256) void k_fused(
    // scatter args
    const int* __restrict__ src, const int* __restrict__ dst,
    int* __restrict__ cursor, unsigned* __restrict__ packed,
    int n_edges, int sbits, int nblk,
    // transform args
    const float* __restrict__ feat, const float* __restrict__ W,
    ushort* __restrict__ g, int n_nodes)
{
    __shared__ __align__(16) char smem[32768];
    int t = threadIdx.x;
    int bid = (int)blockIdx.x;

    if (bid < nblk) {
        // ---------------- bin_scatter body (4096-edge chunk) ----------------
        int* s_cnt  = (int*)smem;                       // 1024 ints
        int* s_base = (int*)(smem + 4096);              // 1024 ints
        int* s_gb   = (int*)(smem + 8192);              // 1024 ints
        int* wtot   = (int*)(smem + 12288);             // 4 ints
        unsigned* s_stage = (unsigned*)(smem + 12304);  // 4096 u32 (ends 28688)

        int chbase = bid * CHS;
        int count = n_edges - chbase;
        if (count > CHS) count = CHS;
        bool full = (count == CHS);

        for (int i = t; i < 1024; i += 256) s_cnt[i] = 0;
        __syncthreads();

        int4 dreg[4], sreg[4];
        if (full) {
            // single global read of dst+src, 16B/lane coalesced
            const int4* d4 = (const int4*)(dst + chbase);
            const int4* s4 = (const int4*)(src + chbase);
            #pragma unroll
            for (int k = 0; k < 4; ++k) {
                dreg[k] = d4[k * 256 + t];
                sreg[k] = s4[k * 256 + t];
            }
            #pragma unroll
            for (int k = 0; k < 4; ++k) {
                atomicAdd(&s_cnt[dreg[k].x >> LOGB], 1);
                atomicAdd(&s_cnt[dreg[k].y >> LOGB], 1);
                atomicAdd(&s_cnt[dreg[k].z >> LOGB], 1);
                atomicAdd(&s_cnt[dreg[k].w >> LOGB], 1);
            }
        } else {
            for (int k = 0; k < 16; ++k) {
                int i = t + k * 256;
                if (i < count) atomicAdd(&s_cnt[dst[chbase + i] >> LOGB], 1);
            }
        }
        __syncthreads();

        int b4 = t * 4;
        int v0 = s_cnt[b4], v1 = s_cnt[b4 + 1], v2 = s_cnt[b4 + 2], v3 = s_cnt[b4 + 3];
        int ssum = v0 + v1 + v2 + v3;
        int lane = t & 63;
        int incl = ssum;
        #pragma unroll
        for (int o = 1; o < 64; o <<= 1) {
            int u = __shfl_up(incl, o, 64);
            if (lane >= o) incl += u;
        }
        if (lane == 63) wtot[t >> 6] = incl;
        __syncthreads();
        int wpre = 0;
        int w = t >> 6;
        for (int i = 0; i < w; ++i) wpre += wtot[i];
        int excl = wpre + incl - ssum;
        s_base[b4]     = excl;
        s_base[b4 + 1] = excl + v0;
        s_base[b4 + 2] = excl + v0 + v1;
        s_base[b4 + 3] = excl + v0 + v1 + v2;
        __syncthreads();

        for (int i = t; i < 1024; i += 256) {
            int c = s_cnt[i];
            s_gb[i] = c ? atomicAdd(&cursor[i], c) : 0;
        }
        __syncthreads();
        for (int i = t; i < 1024; i += 256) s_cnt[i] = s_base[i];
        __syncthreads();

        // pass 2: scatter records into bucket-sorted LDS order (register reuse)
        if (full) {
            #pragma unroll
            for (int k = 0; k < 4; ++k) {
                int d, s, bkt, pos;
                d = dreg[k].x; s = sreg[k].x; bkt = d >> LOGB;
                pos = atomicAdd(&s_cnt[bkt], 1);
                s_stage[pos] = ((unsigned)(d & (BNODES - 1)) << sbits) | (unsigned)s;
                d = dreg[k].y; s = sreg[k].y; bkt = d >> LOGB;
                pos = atomicAdd(&s_cnt[bkt], 1);
                s_stage[pos] = ((unsigned)(d & (BNODES - 1)) << sbits) | (unsigned)s;
                d = dreg[k].z; s = sreg[k].z; bkt = d >> LOGB;
                pos = atomicAdd(&s_cnt[bkt], 1);
                s_stage[pos] = ((unsigned)(d & (BNODES - 1)) << sbits) | (unsigned)s;
                d = dreg[k].w; s = sreg[k].w; bkt = d >> LOGB;
                pos = atomicAdd(&s_cnt[bkt], 1);
                s_stage[pos] = ((unsigned)(d & (BNODES - 1)) << sbits) | (unsigned)s;
            }
        } else {
            for (int k = 0; k < 16; ++k) {
                int i = t + k * 256;
                if (i < count) {
                    int e = chbase + i;
                    int d = dst[e];
                    int s = src[e];
                    int bkt = d >> LOGB;
                    int pos = atomicAdd(&s_cnt[bkt], 1);
                    s_stage[pos] = ((unsigned)(d & (BNODES - 1)) << sbits) | (unsigned)s;
                }
            }
        }
        __syncthreads();

        // pass 3: bucket-owned write-out (ascending addresses per bucket)
        #pragma unroll
        for (int bb = 0; bb < 4; ++bb) {
            int bkt = b4 + bb;
            int lo = s_base[bkt], hi = s_cnt[bkt];
            int gbo = s_gb[bkt];
            for (int i = lo; i < hi; ++i)
                packed[gbo + (i - lo)] = s_stage[i];
        }
    } else {
        // ---------------- transform body: g = bf16(feat @ W) ----------------
        float* ft = (float*)smem;            // 64*64 floats (16KB), XOR-swizzled
        float* Ws = (float*)(smem + 16384);  // 64*64 floats (16KB)

        int tid = bid - nblk;
        int n0 = tid * TN;

        if (tid == 0 && t < 64) g[(size_t)n_nodes * D + t] = 0;   // sentinel row

        {   // stage W, coalesced
            const float4* W4 = (const float4*)W;
            float4* Ws4 = (float4*)Ws;
            #pragma unroll
            for (int i = 0; i < 4; ++i) Ws4[t + i * 256] = W4[t + i * 256];
        }
        {   // stage feat tile transposed + swizzled
            const float4* f4 = (const float4*)feat;
            #pragma unroll
            for (int it = 0; it < 4; ++it) {
                int i = it * 256 + t;
                int r = i >> 4, c = i & 15;
                int node = n0 + r;
                float4 v = (node < n_nodes) ? f4[(size_t)node * 16 + c]
                                            : make_float4(0.f, 0.f, 0.f, 0.f);
                int sw = r ^ (4 * c);
                ft[(4 * c + 0) * 64 + sw] = v.x;
                ft[(4 * c + 1) * 64 + sw] = v.y;
                ft[(4 * c + 2) * 64 + sw] = v.z;
                ft[(4 * c + 3) * 64 + sw] = v.w;
            }
        }
        __syncthreads();

        int nq = t >> 4, cq = t & 15;
        int n4 = nq * 4, c4 = cq * 4;

        float4 a0 = make_float4(0.f, 0.f, 0.f, 0.f);
        float4 a1 = a0, a2 = a0, a3 = a0;

        #pragma unroll 16
        for (int k = 0; k < D; ++k) {
            float4 fv = *reinterpret_cast<const float4*>(&ft[k * 64 + (n4 ^ (k & 60))]);
            float4 wv = *reinterpret_cast<const float4*>(&Ws[k * D + c4]);
            a0.x = fmaf(fv.x, wv.x, a0.x); a0.y = fmaf(fv.x, wv.y, a0.y);
            a0.z = fmaf(fv.x, wv.z, a0.z); a0.w = fmaf(fv.x, wv.w, a0.w);
            a1.x = fmaf(fv.y, wv.x, a1.x); a1.y = fmaf(fv.y, wv.y, a1.y);
            a1.z = fmaf(fv.y, wv.z, a1.z); a1.w = fmaf(fv.y, wv.w, a1.w);
            a2.x = fmaf(fv.z, wv.x, a2.x); a2.y = fmaf(fv.z, wv.y, a2.y);
            a2.z = fmaf(fv.z, wv.z, a2.z); a2.w = fmaf(fv.z, wv.w, a2.w);
            a3.x = fmaf(fv.w, wv.x, a3.x); a3.y = fmaf(fv.w, wv.y, a3.y);
            a3.z = fmaf(fv.w, wv.z, a3.z); a3.w = fmaf(fv.w, wv.w, a3.w);
        }

        float4 accs[4] = {a0, a1, a2, a3};
        #pragma unroll
        for (int i = 0; i < 4; ++i) {
            int node = n0 + n4 + i;
            if (node < n_nodes) {
                ushort4 o;
                o.x = f2bfr(accs[i].x);
                o.y = f2bfr(accs[i].y);
                o.z = f2bfr(accs[i].z);
                o.w = f2bfr(accs[i].w);
                *reinterpret_cast<ushort4*>(g + (size_t)node * D + c4) = o;
            }
        }
    }
}

// ---------------- k_sort128: per-bucket full node sort -> csr2 + noff ----------------

__global__ __launch_bounds__(256) void k_sort128(
    const unsigned* __restrict__ packed,
    const int* __restrict__ bbase,
    int* __restrict__ csr2,
    int* __restrict__ noff,
    int n_nodes, int sbits)
{
    __shared__ int s_cnt[BNODES];
    __shared__ int s_off[BNODES + 1];

    int t = threadIdx.x;
    int b = blockIdx.x;
    int gb = bbase[b], cnt = bbase[b + 1] - gb;

    if (t < BNODES) s_cnt[t] = 0;
    __syncthreads();
    for (int i = t; i < cnt; i += 256)
        atomicAdd(&s_cnt[packed[gb + i] >> sbits], 1);
    __syncthreads();

    if (t < 64) {
        int v0 = s_cnt[2 * t], v1 = s_cnt[2 * t + 1];
        int s = v0 + v1, incl = s;
        #pragma unroll
        for (int o = 1; o < 64; o <<= 1) {
            int u = __shfl_up(incl, o, 64);
            if (t >= o) incl += u;
        }
        int excl = incl - s;
        s_off[2 * t] = excl;
        s_off[2 * t + 1] = excl + v0;
        if (t == 63) s_off[BNODES] = incl;
    }
    __syncthreads();

    if (t <= BNODES) {
        int node = b * BNODES + t;
        if (node <= n_nodes) noff[node] = gb + s_off[t];
    }
    if (t < BNODES) s_cnt[t] = s_off[t];
    __syncthreads();

    unsigned smask = (1u << sbits) - 1u;
    for (int i = t; i < cnt; i += 256) {
        unsigned v = packed[gb + i];
        int pos = atomicAdd(&s_cnt[v >> sbits], 1);
        csr2[gb + pos] = (int)(v & smask);
    }
}

// ---------------- k_bucket6: 32-node blocks over globally-sorted csr2 ----------------

__global__ __launch_bounds__(256) void k_bucket6(
    const ushort* __restrict__ g,      // [(N+1)][64], row N = zeros
    const float* __restrict__ bias,
    const int* __restrict__ noff,      // [N+1]
    const int* __restrict__ csr2,      // [E] srcs sorted by dst
    float* __restrict__ out, int n_nodes)
{
    __shared__ int s_src[CH6];
    __shared__ int s_noff[GRP6 + 1];

    int t = threadIdx.x;
    int n0 = blockIdx.x * GRP6;
    if (t <= GRP6) {
        int node = n0 + t;
        s_noff[t] = noff[node > n_nodes ? n_nodes : node];
    }
    __syncthreads();

    int lane = t & 63, wid = t >> 6;
    int q = lane >> 4;                 // record slot 0..3
    int m = lane & 15;                 // features 4m..4m+3
    const ushort* gm = g + 4 * m;

    float4 acc[8];
    #pragma unroll
    for (int k = 0; k < 8; ++k) acc[k] = make_float4(0.f, 0.f, 0.f, 0.f);

    int beg = s_noff[0], end = s_noff[GRP6];
    for (int cb = beg; cb < end; cb += CH6) {
        int ce = cb + CH6 < end ? cb + CH6 : end;
        __syncthreads();               // protect s_src from previous chunk
        for (int i = cb + t; i < ce; i += 256) s_src[i - cb] = csr2[i];
        __syncthreads();

        #pragma unroll
        for (int k = 0; k < 8; ++k) {
            int r = wid * 8 + k;
            int lo = s_noff[r], hi = s_noff[r + 1];
            if (lo < cb) lo = cb;
            if (hi > ce) hi = ce;
            float4 a = acc[k];
            for (int i = lo; i < hi; i += 16) {
                int i0 = i + q, i1 = i0 + 4, i2 = i0 + 8, i3 = i0 + 12;
                int s0 = (i0 < hi) ? s_src[i0 - cb] : n_nodes;
                int s1 = (i1 < hi) ? s_src[i1 - cb] : n_nodes;
                int s2 = (i2 < hi) ? s_src[i2 - cb] : n_nodes;
                int s3 = (i3 < hi) ? s_src[i3 - cb] : n_nodes;
                uint2 u0 = *reinterpret_cast<const uint2*>(gm + (size_t)s0 * D);
                uint2 u1 = *reinterpret_cast<const uint2*>(gm + (size_t)s1 * D);
                uint2 u2 = *reinterpret_cast<const uint2*>(gm + (size_t)s2 * D);
                uint2 u3 = *reinterpret_cast<const uint2*>(gm + (size_t)s3 * D);
                a.x += blo(u0.x); a.y += bhi(u0.x); a.z += blo(u0.y); a.w += bhi(u0.y);
                a.x += blo(u1.x); a.y += bhi(u1.x); a.z += blo(u1.y); a.w += bhi(u1.y);
                a.x += blo(u2.x); a.y += bhi(u2.x); a.z += blo(u2.y); a.w += bhi(u2.y);
                a.x += blo(u3.x); a.y += bhi(u3.x); a.z += blo(u3.y); a.w += bhi(u3.y);
            }
            acc[k] = a;
        }
    }

    float4 bj = *reinterpret_cast<const float4*>(bias + 4 * m);
    #pragma unroll
    for (int k = 0; k < 8; ++k) {
        float4 v = acc[k];
        v.x += __shfl_xor(v.x, 16, 64);
        v.y += __shfl_xor(v.y, 16, 64);
        v.z += __shfl_xor(v.z, 16, 64);
        v.w += __shfl_xor(v.w, 16, 64);
        v.x += __shfl_xor(v.x, 32, 64);
        v.y += __shfl_xor(v.y, 32, 64);
        v.z += __shfl_xor(v.z, 32, 64);
        v.w += __shfl_xor(v.w, 32, 64);
        if ((k & 3) == q) {
            int r = wid * 8 + k;
            int node = n0 + r;
            if (node < n_nodes) {
                int dgt = s_noff[r + 1] - s_noff[r];
                float4 res;
                if (dgt > 0) {
                    float inv = 1.0f / (float)dgt;
                    res = make_float4(v.x * inv, v.y * inv, v.z * inv, v.w * inv);
                } else {
                    uint2 u = *reinterpret_cast<const uint2*>(gm + (size_t)node * D);
                    res = make_float4(blo(u.x), bhi(u.x), blo(u.y), bhi(u.y));
                }
                res.x = fmaxf(res.x + bj.x, 0.0f);
                res.y = fmaxf(res.y + bj.y, 0.0f);
                res.z = fmaxf(res.z + bj.z, 0.0f);
                res.w = fmaxf(res.w + bj.w, 0.0f);
                *reinterpret_cast<float4*>(out + (size_t)node * D + 4 * m) = res;
            }
        }
    }
}

// ---------------- host ----------------

extern "C" void kernel_launch(void* const* d_in, const int* in_sizes, int n_in,
                              void* d_out, int out_size, void* d_ws, size_t ws_size,
                              hipStream_t stream)
{
    const float* feat = (const float*)d_in[0];
    const int*   src  = (const int*)d_in[1];
    const int*   dst  = (const int*)d_in[2];
    const float* W    = (const float*)d_in[3];
    const float* b    = (const float*)d_in[4];
    float* out = (float*)d_out;

    int n_nodes = in_sizes[0] / D;
    int n_edges = in_sizes[1];
    int nbkt = (n_nodes + BNODES - 1) >> LOGB;

    int sbits = 1;
    while ((1 << sbits) < n_nodes && sbits < 25) sbits++;

    // ws layout: bbase[nbkt+1] | bcnt[nbkt] | bcursor[nbkt] | noff[N+1]
    //            | packed[E] | csr2[E] | g[(N+1)*64] ushort
    size_t base_off   = 0;
    size_t cnt_off    = (((size_t)(nbkt + 1) * 4) + 63) & ~(size_t)63;
    size_t cursor_off = (cnt_off + (size_t)nbkt * 4 + 63) & ~(size_t)63;
    size_t noff_off   = (cursor_off + (size_t)nbkt * 4 + 63) & ~(size_t)63;
    size_t packed_off = (noff_off + ((size_t)n_nodes + 1) * 4 + 63) & ~(size_t)63;
    size_t csr2_off   = (packed_off + (size_t)n_edges * 4 + 63) & ~(size_t)63;
    size_t g_off      = (csr2_off + (size_t)n_edges * 4 + 63) & ~(size_t)63;
    size_t need       = g_off + ((size_t)n_nodes + 1) * D * 2;

    bool ok = (ws_size >= need) && (nbkt <= 1024) && (sbits + LOGB <= 32) &&
              ((1 << sbits) >= n_nodes);
    if (!ok) return;   // cannot happen for this problem's shapes

    char* ws = (char*)d_ws;
    int* bbase   = (int*)(ws + base_off);
    int* bcnt    = (int*)(ws + cnt_off);
    int* bcursor = (int*)(ws + cursor_off);
    int* noff    = (int*)(ws + noff_off);
    unsigned* packed = (unsigned*)(ws + packed_off);
    int* csr2    = (int*)(ws + csr2_off);
    ushort* g    = (ushort*)(ws + g_off);

    int tblk = (n_nodes + TN - 1) / TN;
    int nblk = (n_edges + CHS - 1) / CHS;

    k_zero<<<(nbkt + 255) / 256, 256, 0, stream>>>(bcnt, nbkt);
    k_hist<<<256, 256, 0, stream>>>(dst, bcnt, n_edges, nbkt);
    k_bin_scan<<<1, 1024, 0, stream>>>(bcnt, bbase, bcursor, nbkt);
    k_fused<<<nblk + tblk, 256, 0, stream>>>(src, dst, bcursor, packed,
                                             n_edges, sbits, nblk,
                                             feat, W, g, n_nodes);
    k_sort128<<<nbkt, 256, 0, stream>>>(packed, bbase, csr2, noff,
                                        n_nodes, sbits);
    int ngrp6 = (n_nodes + GRP6 - 1) / GRP6;
    k_bucket6<<<ngrp6, 256, 0, stream>>>(g, b, noff, csr2, out, n_nodes);
}